// Round 7
// baseline (112.755 us; speedup 1.0000x reference)
//
#include <hip/hip_runtime.h>

// EdgeWeightNorm (norm='both'), EPS = 0.
// out[e] = outdeg[src[e]]^-0.5 * indeg[dst[e]]^-0.5 * w[e]
//
// R1/R2: global fp32 atomics execute at the coherence point regardless of
// scope (~20 G atomics/s, 32B write-through each) -> never use them for the
// 12.8M adds. R3: multi-pass LDS histograms (u32 fixed-point, ds_add_u32).
// R4: 160KB LDS -> fewer passes. R5: pack out-deg(lo16)/in-deg(hi16) in one
// u32 -> 3 passes. R6: gather ILP was NULL (59us both ways) -> gather is
// outstanding-request-bound, not ILP-bound. R7 hypothesis: the 800KB norm
// table is evicted from the 4MB/XCD L2 by the gather's own ~100MB streams
// -> many gathers pay L3 latency. Fix: nt-flagged streaming loads (w/src/dst;
// last consumer) and nt output stores (never re-read) in the gather ONLY, so
// the table stays L2-resident. Hist streams stay cacheable (re-read from L3
// across passes).

#define N_NODES 100000
#define TWO_N   (2 * N_NODES)
#define THREADS 1024
#define GT      256            // gather block size
#define SCALE_F   512.0f       // 2^9
#define INV_SCALE 0.001953125f // 2^-9

typedef float vfloat4 __attribute__((ext_vector_type(4)));
typedef int   vint4   __attribute__((ext_vector_type(4)));

// grid = P*C blocks. pass p = bx/C covers nodes [p*bins,(p+1)*bins) for BOTH
// histograms (packed); chunk c = bx%C over edge quads.
__global__ __launch_bounds__(THREADS)
void hist_kernel(const float4* __restrict__ w4,
                 const int4* __restrict__ src4,
                 const int4* __restrict__ dst4,
                 const float* __restrict__ w,
                 const int* __restrict__ src,
                 const int* __restrict__ dst,
                 unsigned* __restrict__ parts,
                 int n4, int n_edges, int P, int C, int bins, int chunk4)
{
    extern __shared__ unsigned lds[];
    const int j = blockIdx.x / C;           // node-range pass
    const int c = blockIdx.x - j * C;       // edge chunk
    const int lo = j * bins;

    for (int k = threadIdx.x; k < bins; k += THREADS) lds[k] = 0;
    __syncthreads();

    const int beg = c * chunk4;
    const int end = min(n4, beg + chunk4);

#define QUAD(wv, sv, dv)                                                      \
    do {                                                                      \
        unsigned v0 = (unsigned)((wv).x * SCALE_F + 0.5f);                    \
        unsigned v1 = (unsigned)((wv).y * SCALE_F + 0.5f);                    \
        unsigned v2 = (unsigned)((wv).z * SCALE_F + 0.5f);                    \
        unsigned v3 = (unsigned)((wv).w * SCALE_F + 0.5f);                    \
        int a0 = (sv).x - lo, a1 = (sv).y - lo, a2 = (sv).z - lo, a3 = (sv).w - lo; \
        int b0 = (dv).x - lo, b1 = (dv).y - lo, b2 = (dv).z - lo, b3 = (dv).w - lo; \
        if ((unsigned)a0 < (unsigned)bins) atomicAdd(&lds[a0], v0);           \
        if ((unsigned)a1 < (unsigned)bins) atomicAdd(&lds[a1], v1);           \
        if ((unsigned)a2 < (unsigned)bins) atomicAdd(&lds[a2], v2);           \
        if ((unsigned)a3 < (unsigned)bins) atomicAdd(&lds[a3], v3);           \
        if ((unsigned)b0 < (unsigned)bins) atomicAdd(&lds[b0], v0 << 16);     \
        if ((unsigned)b1 < (unsigned)bins) atomicAdd(&lds[b1], v1 << 16);     \
        if ((unsigned)b2 < (unsigned)bins) atomicAdd(&lds[b2], v2 << 16);     \
        if ((unsigned)b3 < (unsigned)bins) atomicAdd(&lds[b3], v3 << 16);     \
    } while (0)

    int i = beg + (int)threadIdx.x;
    for (; i + 3 * THREADS < end; i += 4 * THREADS) {
        float4 wa = w4[i];
        float4 wb = w4[i + THREADS];
        float4 wc = w4[i + 2 * THREADS];
        float4 wd = w4[i + 3 * THREADS];
        int4 sa = src4[i];
        int4 sb = src4[i + THREADS];
        int4 sc = src4[i + 2 * THREADS];
        int4 sd = src4[i + 3 * THREADS];
        int4 da = dst4[i];
        int4 db = dst4[i + THREADS];
        int4 dc = dst4[i + 2 * THREADS];
        int4 dd = dst4[i + 3 * THREADS];
        QUAD(wa, sa, da);
        QUAD(wb, sb, db);
        QUAD(wc, sc, dc);
        QUAD(wd, sd, dd);
    }
    for (; i < end; i += THREADS) {
        float4 wa = w4[i];
        int4 sa = src4[i];
        int4 da = dst4[i];
        QUAD(wa, sa, da);
    }
#undef QUAD

    // tail (n_edges % 4), once, by the last chunk of each pass (empty for
    // E=6.4M; kept for generality)
    if (c == C - 1 && threadIdx.x == 0) {
        for (int e = n4 * 4; e < n_edges; ++e) {
            unsigned v = (unsigned)(w[e] * SCALE_F + 0.5f);
            int a = src[e] - lo;
            int b = dst[e] - lo;
            if ((unsigned)a < (unsigned)bins) atomicAdd(&lds[a], v);
            if ((unsigned)b < (unsigned)bins) atomicAdd(&lds[b], v << 16);
        }
    }

    __syncthreads();
    unsigned* op = parts + ((size_t)j * C + c) * bins;
    for (int k = threadIdx.x; k < bins; k += THREADS)
        __builtin_nontemporal_store(lds[k], op + k);   // bulk dump
}

__global__ void reduce_rsqrt_kernel(const unsigned* __restrict__ parts,
                                    float* __restrict__ norm,
                                    int P, int C, int bins)
{
    int i = blockIdx.x * blockDim.x + threadIdx.x;
    if (i >= N_NODES) return;
    int p = i / bins;
    int b = i - p * bins;
    const unsigned* base = parts + ((size_t)p * C) * bins + b;
    unsigned lo0 = 0, hi0 = 0, lo1 = 0, hi1 = 0, lo2 = 0, hi2 = 0, lo3 = 0, hi3 = 0;
    int c = 0;
    for (; c + 3 < C; c += 4) {
        unsigned v0 = base[(size_t)(c + 0) * bins];
        unsigned v1 = base[(size_t)(c + 1) * bins];
        unsigned v2 = base[(size_t)(c + 2) * bins];
        unsigned v3 = base[(size_t)(c + 3) * bins];
        lo0 += v0 & 0xFFFFu; hi0 += v0 >> 16;
        lo1 += v1 & 0xFFFFu; hi1 += v1 >> 16;
        lo2 += v2 & 0xFFFFu; hi2 += v2 >> 16;
        lo3 += v3 & 0xFFFFu; hi3 += v3 >> 16;
    }
    for (; c < C; ++c) {
        unsigned v = base[(size_t)c * bins];
        lo0 += v & 0xFFFFu; hi0 += v >> 16;
    }
    unsigned lo_s = lo0 + lo1 + lo2 + lo3;
    unsigned hi_s = hi0 + hi1 + hi2 + hi3;
    // deg==0 -> inf matches 0**-0.5
    norm[i]           = 1.0f / sqrtf((float)lo_s * INV_SCALE);
    norm[N_NODES + i] = 1.0f / sqrtf((float)hi_s * INV_SCALE);
}

// ---- fallback path (ws too small): device atomics, R1 style ----
__global__ void degree_atomic_kernel(const float* __restrict__ w,
                                     const int* __restrict__ src,
                                     const int* __restrict__ dst,
                                     float* __restrict__ deg,
                                     int n_edges)
{
    int i = blockIdx.x * blockDim.x + threadIdx.x;
    int stride = gridDim.x * blockDim.x;
    for (; i < n_edges; i += stride) {
        float wi = w[i];
        atomicAdd(&deg[src[i]], wi);
        atomicAdd(&deg[N_NODES + dst[i]], wi);
    }
}

__global__ void rsqrt_kernel(float* __restrict__ p, int n)
{
    int i = blockIdx.x * blockDim.x + threadIdx.x;
    if (i < n) p[i] = 1.0f / sqrtf(p[i]);
}

// ---- output pass: 2 quads/thread. ALL streaming traffic (edge reads, out
// writes) is nt-flagged so it does not evict the 800KB norm table from the
// per-XCD L2; the 16 random table gathers per thread stay L2-hit. ----
__global__ __launch_bounds__(GT)
void gather4_kernel(const float4* __restrict__ w4,
                    const int4* __restrict__ src4,
                    const int4* __restrict__ dst4,
                    const float* __restrict__ srcn,
                    const float* __restrict__ dstn,
                    float4* __restrict__ out4,
                    int n4, int n_edges,
                    const float* __restrict__ w,
                    const int* __restrict__ src,
                    const int* __restrict__ dst,
                    float* __restrict__ out)
{
    const int q0 = blockIdx.x * (2 * GT) + threadIdx.x;
    const int q1 = q0 + GT;
    const bool p0 = q0 < n4;
    const bool p1 = q1 < n4;

    vfloat4 w0, w1;
    vint4 s0, s1, d0, d1;
    if (p0) {
        w0 = __builtin_nontemporal_load((const vfloat4*)&w4[q0]);
        s0 = __builtin_nontemporal_load((const vint4*)&src4[q0]);
        d0 = __builtin_nontemporal_load((const vint4*)&dst4[q0]);
    }
    if (p1) {
        w1 = __builtin_nontemporal_load((const vfloat4*)&w4[q1]);
        s1 = __builtin_nontemporal_load((const vint4*)&src4[q1]);
        d1 = __builtin_nontemporal_load((const vint4*)&dst4[q1]);
    }

    if (p0) {
        vfloat4 o;
        o.x = srcn[s0.x] * dstn[d0.x] * w0.x;
        o.y = srcn[s0.y] * dstn[d0.y] * w0.y;
        o.z = srcn[s0.z] * dstn[d0.z] * w0.z;
        o.w = srcn[s0.w] * dstn[d0.w] * w0.w;
        __builtin_nontemporal_store(o, (vfloat4*)&out4[q0]);
    }
    if (p1) {
        vfloat4 o;
        o.x = srcn[s1.x] * dstn[d1.x] * w1.x;
        o.y = srcn[s1.y] * dstn[d1.y] * w1.y;
        o.z = srcn[s1.z] * dstn[d1.z] * w1.z;
        o.w = srcn[s1.w] * dstn[d1.w] * w1.w;
        __builtin_nontemporal_store(o, (vfloat4*)&out4[q1]);
    }

    // tail (n_edges % 4 == 0 here; kept for generality)
    if (blockIdx.x == 0 && threadIdx.x == 0) {
        for (int e = n4 * 4; e < n_edges; ++e)
            out[e] = srcn[src[e]] * dstn[dst[e]] * w[e];
    }
}

extern "C" void kernel_launch(void* const* d_in, const int* in_sizes, int n_in,
                              void* d_out, int out_size, void* d_ws, size_t ws_size,
                              hipStream_t stream)
{
    const float* w   = (const float*)d_in[0];
    const int*   src = (const int*)d_in[1];
    const int*   dst = (const int*)d_in[2];
    const int E  = in_sizes[0];
    const int n4 = E >> 2;
    float* out = (float*)d_out;

    float* norm = (float*)d_ws;                 // [0,N) src_norm, [N,2N) dst_norm
    unsigned* parts = (unsigned*)(norm + TWO_N);
    size_t ws_u = ws_size / 4;
    size_t avail_u = (ws_u > (size_t)(TWO_N + 16)) ? ws_u - TWO_N - 16 : 0;

    // Biggest dynamic-LDS grant: 160KB (full CU) -> 128 -> 80 -> default 64KB.
    int lds_bytes = 65536;
    {
        const int cands[3] = {163840, 131072, 81920};
        for (int t = 0; t < 3; ++t) {
            if (hipFuncSetAttribute((const void*)hist_kernel,
                                    hipFuncAttributeMaxDynamicSharedMemorySize,
                                    cands[t]) == hipSuccess) {
                lds_bytes = cands[t];
                break;
            }
        }
    }
    const int bins = lds_bytes / 4;
    const int P = (N_NODES + bins - 1) / bins;   // packed: P passes cover BOTH hists

    // grid cap = co-resident capacity (1 block/CU at 160KB) so no trailing
    // serialized blocks.
    const int blk_per_cu = 163840 / lds_bytes;
    int C = (256 * blk_per_cu) / P;
    const size_t per_chunk_u = (size_t)P * (size_t)bins;
    if (avail_u < per_chunk_u) C = 0;
    else {
        int cmax = (int)(avail_u / per_chunk_u);
        if (C > cmax) C = cmax;
    }

    if (C >= 1) {
        const int chunk4 = (n4 + C - 1) / C;
        hist_kernel<<<P * C, THREADS, (size_t)lds_bytes, stream>>>(
            (const float4*)w, (const int4*)src, (const int4*)dst,
            w, src, dst, parts, n4, E, P, C, bins, chunk4);
        reduce_rsqrt_kernel<<<(N_NODES + 255) / 256, 256, 0, stream>>>(parts, norm, P, C, bins);
    } else {
        hipMemsetAsync(norm, 0, (size_t)TWO_N * sizeof(float), stream);
        degree_atomic_kernel<<<2048, 256, 0, stream>>>(w, src, dst, norm, E);
        rsqrt_kernel<<<(TWO_N + 255) / 256, 256, 0, stream>>>(norm, TWO_N);
    }

    {
        int grid = (n4 + 2 * GT - 1) / (2 * GT);
        if (grid < 1) grid = 1;
        gather4_kernel<<<grid, GT, 0, stream>>>(
            (const float4*)w, (const int4*)src, (const int4*)dst,
            norm, norm + N_NODES, (float4*)out,
            n4, E, w, src, dst, out);
    }
}

// Round 8
// 91.367 us; speedup vs baseline: 1.2341x; 1.2341x over previous
//
#include <hip/hip_runtime.h>
#include <hip/hip_fp16.h>

// EdgeWeightNorm (norm='both'), EPS = 0.
// out[e] = outdeg[src[e]]^-0.5 * indeg[dst[e]]^-0.5 * w[e]
//
// Journal:
// R1/R2: global fp32 atomics execute at the coherence point regardless of
//   scope (~20 G atomics/s, 32B write-through each) -> never use them.
// R3: multi-pass LDS histograms (u32 fixed-point, ds_add_u32).
// R4: 160KB LDS -> fewer passes. R5: pack outdeg(lo16)/indeg(hi16) in one
//   u32 -> 3 passes cover both degree sums.
// R6/R7: gather pass is pinned at 59us regardless of ILP / NT hints ->
//   per-CU outstanding-miss (MSHR x latency) cap on random vector-memory
//   gathers (0.35 lines/cy/CU).
// R8: gather via LDS instead: norm tables stored f16 (81920 entries per
//   160KB slice -> 2 passes per table). Each block holds its edge chunk in
//   REGISTERS (7 quads/thread, fully unrolled -> no scratch), loops 4 slice
//   passes (2 src + 2 dst), ds_read_u16 gathers (no MSHR limit), one store.

#define N_NODES 100000
#define TWO_N   (2 * N_NODES)
#define THREADS 1024
#define GBLK    1024
#define KMAX    7              // quads per thread (7*1024 = 7168 >= 6250)
#define SCALE_F   512.0f       // 2^9
#define INV_SCALE 0.001953125f // 2^-9

// ---------------- degree histogram (unchanged from R5/R6) ----------------
// grid = P*C blocks. pass p = bx/C covers nodes [p*bins,(p+1)*bins) for BOTH
// histograms (packed u16 halves); chunk c = bx%C over edge quads.
__global__ __launch_bounds__(THREADS)
void hist_kernel(const float4* __restrict__ w4,
                 const int4* __restrict__ src4,
                 const int4* __restrict__ dst4,
                 const float* __restrict__ w,
                 const int* __restrict__ src,
                 const int* __restrict__ dst,
                 unsigned* __restrict__ parts,
                 int n4, int n_edges, int P, int C, int bins, int chunk4)
{
    extern __shared__ unsigned lds[];
    const int j = blockIdx.x / C;
    const int c = blockIdx.x - j * C;
    const int lo = j * bins;

    for (int k = threadIdx.x; k < bins; k += THREADS) lds[k] = 0;
    __syncthreads();

    const int beg = c * chunk4;
    const int end = min(n4, beg + chunk4);

#define QUAD(wv, sv, dv)                                                      \
    do {                                                                      \
        unsigned v0 = (unsigned)((wv).x * SCALE_F + 0.5f);                    \
        unsigned v1 = (unsigned)((wv).y * SCALE_F + 0.5f);                    \
        unsigned v2 = (unsigned)((wv).z * SCALE_F + 0.5f);                    \
        unsigned v3 = (unsigned)((wv).w * SCALE_F + 0.5f);                    \
        int a0 = (sv).x - lo, a1 = (sv).y - lo, a2 = (sv).z - lo, a3 = (sv).w - lo; \
        int b0 = (dv).x - lo, b1 = (dv).y - lo, b2 = (dv).z - lo, b3 = (dv).w - lo; \
        if ((unsigned)a0 < (unsigned)bins) atomicAdd(&lds[a0], v0);           \
        if ((unsigned)a1 < (unsigned)bins) atomicAdd(&lds[a1], v1);           \
        if ((unsigned)a2 < (unsigned)bins) atomicAdd(&lds[a2], v2);           \
        if ((unsigned)a3 < (unsigned)bins) atomicAdd(&lds[a3], v3);           \
        if ((unsigned)b0 < (unsigned)bins) atomicAdd(&lds[b0], v0 << 16);     \
        if ((unsigned)b1 < (unsigned)bins) atomicAdd(&lds[b1], v1 << 16);     \
        if ((unsigned)b2 < (unsigned)bins) atomicAdd(&lds[b2], v2 << 16);     \
        if ((unsigned)b3 < (unsigned)bins) atomicAdd(&lds[b3], v3 << 16);     \
    } while (0)

    int i = beg + (int)threadIdx.x;
    for (; i + 3 * THREADS < end; i += 4 * THREADS) {
        float4 wa = w4[i];
        float4 wb = w4[i + THREADS];
        float4 wc = w4[i + 2 * THREADS];
        float4 wd = w4[i + 3 * THREADS];
        int4 sa = src4[i];
        int4 sb = src4[i + THREADS];
        int4 sc = src4[i + 2 * THREADS];
        int4 sd = src4[i + 3 * THREADS];
        int4 da = dst4[i];
        int4 db = dst4[i + THREADS];
        int4 dc = dst4[i + 2 * THREADS];
        int4 dd = dst4[i + 3 * THREADS];
        QUAD(wa, sa, da);
        QUAD(wb, sb, db);
        QUAD(wc, sc, dc);
        QUAD(wd, sd, dd);
    }
    for (; i < end; i += THREADS) {
        float4 wa = w4[i];
        int4 sa = src4[i];
        int4 da = dst4[i];
        QUAD(wa, sa, da);
    }
#undef QUAD

    if (c == C - 1 && threadIdx.x == 0) {        // tail edges (none for E=6.4M)
        for (int e = n4 * 4; e < n_edges; ++e) {
            unsigned v = (unsigned)(w[e] * SCALE_F + 0.5f);
            int a = src[e] - lo;
            int b = dst[e] - lo;
            if ((unsigned)a < (unsigned)bins) atomicAdd(&lds[a], v);
            if ((unsigned)b < (unsigned)bins) atomicAdd(&lds[b], v << 16);
        }
    }

    __syncthreads();
    unsigned* op = parts + ((size_t)j * C + c) * bins;
    for (int k = threadIdx.x; k < bins; k += THREADS)
        __builtin_nontemporal_store(lds[k], op + k);   // bulk dump
}

// ------------- reduce partials -> f16 norm tables (deg^-0.5) -------------
__global__ void reduce_rsqrt_kernel(const unsigned* __restrict__ parts,
                                    __half* __restrict__ normh,
                                    int P, int C, int bins)
{
    int i = blockIdx.x * blockDim.x + threadIdx.x;
    if (i >= N_NODES) return;
    int p = i / bins;
    int b = i - p * bins;
    const unsigned* base = parts + ((size_t)p * C) * bins + b;
    unsigned lo0 = 0, hi0 = 0, lo1 = 0, hi1 = 0, lo2 = 0, hi2 = 0, lo3 = 0, hi3 = 0;
    int c = 0;
    for (; c + 3 < C; c += 4) {
        unsigned v0 = base[(size_t)(c + 0) * bins];
        unsigned v1 = base[(size_t)(c + 1) * bins];
        unsigned v2 = base[(size_t)(c + 2) * bins];
        unsigned v3 = base[(size_t)(c + 3) * bins];
        lo0 += v0 & 0xFFFFu; hi0 += v0 >> 16;
        lo1 += v1 & 0xFFFFu; hi1 += v1 >> 16;
        lo2 += v2 & 0xFFFFu; hi2 += v2 >> 16;
        lo3 += v3 & 0xFFFFu; hi3 += v3 >> 16;
    }
    for (; c < C; ++c) {
        unsigned v = base[(size_t)c * bins];
        lo0 += v & 0xFFFFu; hi0 += v >> 16;
    }
    unsigned lo_s = lo0 + lo1 + lo2 + lo3;
    unsigned hi_s = hi0 + hi1 + hi2 + hi3;
    // deg==0 -> inf matches 0**-0.5 (never gathered: an edge implies deg>0)
    normh[i]           = __float2half(1.0f / sqrtf((float)lo_s * INV_SCALE));
    normh[N_NODES + i] = __float2half(1.0f / sqrtf((float)hi_s * INV_SCALE));
}

// ---------------- fallback path (tiny ws): device atomics ----------------
__global__ void degree_atomic_kernel(const float* __restrict__ w,
                                     const int* __restrict__ src,
                                     const int* __restrict__ dst,
                                     float* __restrict__ deg,
                                     int n_edges)
{
    int i = blockIdx.x * blockDim.x + threadIdx.x;
    int stride = gridDim.x * blockDim.x;
    for (; i < n_edges; i += stride) {
        float wi = w[i];
        atomicAdd(&deg[src[i]], wi);
        atomicAdd(&deg[N_NODES + dst[i]], wi);
    }
}

__global__ void rsqrt_half_kernel(const float* __restrict__ deg,
                                  __half* __restrict__ normh, int n)
{
    int i = blockIdx.x * blockDim.x + threadIdx.x;
    if (i < n) normh[i] = __float2half(1.0f / sqrtf(deg[i]));
}

// ------- output pass: edges in registers, norm slices in LDS (f16) -------
// Block owns quads [q0, q0+qpb). 4 slice passes: {srcn,dstn} x {0..P-1}.
// All per-quad arrays indexed by compile-time k (full unroll) -> registers.
__global__ __launch_bounds__(GBLK)
void prod_kernel(const float4* __restrict__ w4,
                 const int4* __restrict__ src4,
                 const int4* __restrict__ dst4,
                 const __half* __restrict__ srcn_h,
                 const __half* __restrict__ dstn_h,
                 float4* __restrict__ out4,
                 int n4, int n_edges, int qpb, int binsh,
                 const float* __restrict__ w,
                 const int* __restrict__ src,
                 const int* __restrict__ dst,
                 float* __restrict__ out)
{
    extern __shared__ __half lh[];
    const int q0   = blockIdx.x * qpb;
    const int qend = min(n4, q0 + qpb);
    const int t    = threadIdx.x;

    float4 pr[KMAX];
    int4   sv[KMAX], dv[KMAX];
    bool   val[KMAX];

#pragma unroll
    for (int k = 0; k < KMAX; ++k) {
        const int q = q0 + k * GBLK + t;
        val[k] = q < qend;
        if (val[k]) {
            pr[k] = w4[q];        // product accumulator starts at w
            sv[k] = src4[q];
            dv[k] = dst4[q];
        }
    }

    for (int phase = 0; phase < 2; ++phase) {
        const __half* tab = phase ? dstn_h : srcn_h;
        for (int lo = 0; lo < N_NODES; lo += binsh) {
            const int len = min(binsh, N_NODES - lo);
            // fill LDS slice: vectorized uint4 (8 halves) + scalar tail
            const int len8 = len >> 3;
            const uint4* tsrc = (const uint4*)(tab + lo);
            uint4* ldst = (uint4*)lh;
            for (int k2 = t; k2 < len8; k2 += GBLK) ldst[k2] = tsrc[k2];
            for (int k2 = (len8 << 3) + t; k2 < len; k2 += GBLK) lh[k2] = tab[lo + k2];
            __syncthreads();

#pragma unroll
            for (int k = 0; k < KMAX; ++k) {
                if (!val[k]) continue;
                const int4 iv = phase ? dv[k] : sv[k];
                unsigned a;
                a = (unsigned)(iv.x - lo); if (a < (unsigned)len) pr[k].x *= __half2float(lh[a]);
                a = (unsigned)(iv.y - lo); if (a < (unsigned)len) pr[k].y *= __half2float(lh[a]);
                a = (unsigned)(iv.z - lo); if (a < (unsigned)len) pr[k].z *= __half2float(lh[a]);
                a = (unsigned)(iv.w - lo); if (a < (unsigned)len) pr[k].w *= __half2float(lh[a]);
            }
            __syncthreads();   // before next slice overwrites LDS
        }
    }

#pragma unroll
    for (int k = 0; k < KMAX; ++k) {
        const int q = q0 + k * GBLK + t;
        if (val[k]) out4[q] = pr[k];
    }

    // tail edges (n_edges % 4 == 0 here; direct global gather, few edges)
    if (blockIdx.x == 0 && t == 0) {
        for (int e = n4 * 4; e < n_edges; ++e)
            out[e] = __half2float(srcn_h[src[e]]) * __half2float(dstn_h[dst[e]]) * w[e];
    }
}

extern "C" void kernel_launch(void* const* d_in, const int* in_sizes, int n_in,
                              void* d_out, int out_size, void* d_ws, size_t ws_size,
                              hipStream_t stream)
{
    const float* w   = (const float*)d_in[0];
    const int*   src = (const int*)d_in[1];
    const int*   dst = (const int*)d_in[2];
    const int E  = in_sizes[0];
    const int n4 = E >> 2;
    float* out = (float*)d_out;

    // ws layout: [0, 400KB) f16 norm tables (srcn | dstn); [1MB, ...) scratch
    __half* normh = (__half*)d_ws;
    char* scratch = (char*)d_ws + (1 << 20);
    unsigned* parts = (unsigned*)scratch;
    float* degf = (float*)scratch;               // fallback f32 degrees
    size_t avail_u = (ws_size > (1u << 20)) ? (ws_size - (1 << 20)) / 4 : 0;

    // Biggest dynamic-LDS grant per kernel: 160KB -> 128 -> 80 -> 64KB.
    const int cands[3] = {163840, 131072, 81920};
    int lds_hist = 65536;
    for (int tC = 0; tC < 3; ++tC)
        if (hipFuncSetAttribute((const void*)hist_kernel,
                                hipFuncAttributeMaxDynamicSharedMemorySize,
                                cands[tC]) == hipSuccess) { lds_hist = cands[tC]; break; }
    int lds_prod = 65536;
    for (int tC = 0; tC < 3; ++tC)
        if (hipFuncSetAttribute((const void*)prod_kernel,
                                hipFuncAttributeMaxDynamicSharedMemorySize,
                                cands[tC]) == hipSuccess) { lds_prod = cands[tC]; break; }

    const int bins = lds_hist / 4;               // u32 packed degree counters
    const int P = (N_NODES + bins - 1) / bins;

    const int blk_per_cu = 163840 / lds_hist;
    int C = (256 * blk_per_cu) / P;
    const size_t per_chunk_u = (size_t)P * (size_t)bins;
    if (avail_u < per_chunk_u) C = 0;
    else {
        int cmax = (int)(avail_u / per_chunk_u);
        if (C > cmax) C = cmax;
    }

    if (C >= 1) {
        const int chunk4 = (n4 + C - 1) / C;
        hist_kernel<<<P * C, THREADS, (size_t)lds_hist, stream>>>(
            (const float4*)w, (const int4*)src, (const int4*)dst,
            w, src, dst, parts, n4, E, P, C, bins, chunk4);
        reduce_rsqrt_kernel<<<(N_NODES + 255) / 256, 256, 0, stream>>>(
            parts, normh, P, C, bins);
    } else {
        hipMemsetAsync(degf, 0, (size_t)TWO_N * sizeof(float), stream);
        degree_atomic_kernel<<<2048, 256, 0, stream>>>(w, src, dst, degf, E);
        rsqrt_half_kernel<<<(TWO_N + 255) / 256, 256, 0, stream>>>(degf, normh, TWO_N);
    }

    {
        const int binsh = lds_prod / 2;          // f16 entries per slice
        const int maxq = KMAX * GBLK;            // 7168 quads/block capacity
        int C2 = (n4 + maxq - 1) / maxq;
        if (C2 < 256) C2 = 256;                  // fill all CUs
        const int qpb = (n4 + C2 - 1) / C2;      // <= 7168 by construction
        prod_kernel<<<C2, GBLK, (size_t)lds_prod, stream>>>(
            (const float4*)w, (const int4*)src, (const int4*)dst,
            normh, normh + N_NODES, (float4*)out,
            n4, E, qpb, binsh, w, src, dst, out);
    }
}

// Round 9
// 71.907 us; speedup vs baseline: 1.5681x; 1.2706x over previous
//
#include <hip/hip_runtime.h>
#include <hip/hip_fp16.h>

// EdgeWeightNorm (norm='both'), EPS = 0.
// out[e] = outdeg[src[e]]^-0.5 * indeg[dst[e]]^-0.5 * w[e]
//
// Journal:
// R1/R2: global fp32 atomics go to the coherence point regardless of scope
//   (~20 G atomics/s, 32B write-through each) -> never use them.
// R3: multi-pass LDS histograms (u32 fixed-point, ds_add_u32).
// R4: 160KB LDS -> fewer passes. R5: pack outdeg(lo16)/indeg(hi16) in one
//   u32 -> 3 passes cover both degree sums.
// R6/R7: random vector-memory gathers pinned by per-CU outstanding-miss cap
//   (0.35 lines/cy/CU); ILP and NT hints null.
// R8: output pass gathers from LDS-resident f16 norm slices (edges held in
//   registers, 4 slice passes) -> 59us gather gone. hist (42us) now top:
//   model says outstanding-line x latency bound (FETCH 112MB, 2.7TB/s only).
// R9: XCD co-scheduling swizzle for hist: the 3 pass-blocks sharing chunk c
//   land on the same XCD (C=80 multiple of 8; x=bid&7, j=(bid>>3)%P,
//   c=x+8*((bid>>3)/P)) -> 2/3 of chunk reads become L2 hits (~200cy vs
//   ~600cy L3) -> latency-capped throughput rises.

#define N_NODES 100000
#define TWO_N   (2 * N_NODES)
#define THREADS 1024
#define GBLK    1024
#define KMAX    7              // quads per thread in prod (7*1024 >= 6250)
#define SCALE_F   512.0f       // 2^9
#define INV_SCALE 0.001953125f // 2^-9

// ---------------- degree histogram ----------------
// grid = P*C blocks. pass j covers nodes [j*bins,(j+1)*bins) for BOTH
// histograms (packed u16 halves); chunk c over edge quads.
// swz!=0 requires C%8==0: same-chunk triples co-resident on one XCD.
__global__ __launch_bounds__(THREADS)
void hist_kernel(const float4* __restrict__ w4,
                 const int4* __restrict__ src4,
                 const int4* __restrict__ dst4,
                 const float* __restrict__ w,
                 const int* __restrict__ src,
                 const int* __restrict__ dst,
                 unsigned* __restrict__ parts,
                 int n4, int n_edges, int P, int C, int bins, int chunk4,
                 int swz)
{
    extern __shared__ unsigned lds[];
    int j, c;
    if (swz) {
        const int x = blockIdx.x & 7;
        const int r = blockIdx.x >> 3;
        j = r % P;
        c = x + 8 * (r / P);
    } else {
        j = blockIdx.x / C;
        c = blockIdx.x - j * C;
    }
    const int lo = j * bins;

    for (int k = threadIdx.x; k < bins; k += THREADS) lds[k] = 0;
    __syncthreads();

    const int beg = c * chunk4;
    const int end = min(n4, beg + chunk4);

#define QUAD(wv, sv, dv)                                                      \
    do {                                                                      \
        unsigned v0 = (unsigned)((wv).x * SCALE_F + 0.5f);                    \
        unsigned v1 = (unsigned)((wv).y * SCALE_F + 0.5f);                    \
        unsigned v2 = (unsigned)((wv).z * SCALE_F + 0.5f);                    \
        unsigned v3 = (unsigned)((wv).w * SCALE_F + 0.5f);                    \
        int a0 = (sv).x - lo, a1 = (sv).y - lo, a2 = (sv).z - lo, a3 = (sv).w - lo; \
        int b0 = (dv).x - lo, b1 = (dv).y - lo, b2 = (dv).z - lo, b3 = (dv).w - lo; \
        if ((unsigned)a0 < (unsigned)bins) atomicAdd(&lds[a0], v0);           \
        if ((unsigned)a1 < (unsigned)bins) atomicAdd(&lds[a1], v1);           \
        if ((unsigned)a2 < (unsigned)bins) atomicAdd(&lds[a2], v2);           \
        if ((unsigned)a3 < (unsigned)bins) atomicAdd(&lds[a3], v3);           \
        if ((unsigned)b0 < (unsigned)bins) atomicAdd(&lds[b0], v0 << 16);     \
        if ((unsigned)b1 < (unsigned)bins) atomicAdd(&lds[b1], v1 << 16);     \
        if ((unsigned)b2 < (unsigned)bins) atomicAdd(&lds[b2], v2 << 16);     \
        if ((unsigned)b3 < (unsigned)bins) atomicAdd(&lds[b3], v3 << 16);     \
    } while (0)

    int i = beg + (int)threadIdx.x;
    for (; i + 3 * THREADS < end; i += 4 * THREADS) {
        float4 wa = w4[i];
        float4 wb = w4[i + THREADS];
        float4 wc = w4[i + 2 * THREADS];
        float4 wd = w4[i + 3 * THREADS];
        int4 sa = src4[i];
        int4 sb = src4[i + THREADS];
        int4 sc = src4[i + 2 * THREADS];
        int4 sd = src4[i + 3 * THREADS];
        int4 da = dst4[i];
        int4 db = dst4[i + THREADS];
        int4 dc = dst4[i + 2 * THREADS];
        int4 dd = dst4[i + 3 * THREADS];
        QUAD(wa, sa, da);
        QUAD(wb, sb, db);
        QUAD(wc, sc, dc);
        QUAD(wd, sd, dd);
    }
    for (; i < end; i += THREADS) {
        float4 wa = w4[i];
        int4 sa = src4[i];
        int4 da = dst4[i];
        QUAD(wa, sa, da);
    }
#undef QUAD

    if (c == C - 1 && threadIdx.x == 0) {        // tail edges (none for E=6.4M)
        for (int e = n4 * 4; e < n_edges; ++e) {
            unsigned v = (unsigned)(w[e] * SCALE_F + 0.5f);
            int a = src[e] - lo;
            int b = dst[e] - lo;
            if ((unsigned)a < (unsigned)bins) atomicAdd(&lds[a], v);
            if ((unsigned)b < (unsigned)bins) atomicAdd(&lds[b], v << 16);
        }
    }

    __syncthreads();
    unsigned* op = parts + ((size_t)j * C + c) * bins;
    for (int k = threadIdx.x; k < bins; k += THREADS)
        __builtin_nontemporal_store(lds[k], op + k);   // bulk dump
}

// ------------- reduce partials -> f16 norm tables (deg^-0.5) -------------
__global__ void reduce_rsqrt_kernel(const unsigned* __restrict__ parts,
                                    __half* __restrict__ normh,
                                    int P, int C, int bins)
{
    int i = blockIdx.x * blockDim.x + threadIdx.x;
    if (i >= N_NODES) return;
    int p = i / bins;
    int b = i - p * bins;
    const unsigned* base = parts + ((size_t)p * C) * bins + b;
    unsigned lo0 = 0, hi0 = 0, lo1 = 0, hi1 = 0, lo2 = 0, hi2 = 0, lo3 = 0, hi3 = 0;
    int c = 0;
    for (; c + 3 < C; c += 4) {
        unsigned v0 = base[(size_t)(c + 0) * bins];
        unsigned v1 = base[(size_t)(c + 1) * bins];
        unsigned v2 = base[(size_t)(c + 2) * bins];
        unsigned v3 = base[(size_t)(c + 3) * bins];
        lo0 += v0 & 0xFFFFu; hi0 += v0 >> 16;
        lo1 += v1 & 0xFFFFu; hi1 += v1 >> 16;
        lo2 += v2 & 0xFFFFu; hi2 += v2 >> 16;
        lo3 += v3 & 0xFFFFu; hi3 += v3 >> 16;
    }
    for (; c < C; ++c) {
        unsigned v = base[(size_t)c * bins];
        lo0 += v & 0xFFFFu; hi0 += v >> 16;
    }
    unsigned lo_s = lo0 + lo1 + lo2 + lo3;
    unsigned hi_s = hi0 + hi1 + hi2 + hi3;
    // deg==0 -> inf matches 0**-0.5 (never gathered: an edge implies deg>0)
    normh[i]           = __float2half(1.0f / sqrtf((float)lo_s * INV_SCALE));
    normh[N_NODES + i] = __float2half(1.0f / sqrtf((float)hi_s * INV_SCALE));
}

// ---------------- fallback path (tiny ws): device atomics ----------------
__global__ void degree_atomic_kernel(const float* __restrict__ w,
                                     const int* __restrict__ src,
                                     const int* __restrict__ dst,
                                     float* __restrict__ deg,
                                     int n_edges)
{
    int i = blockIdx.x * blockDim.x + threadIdx.x;
    int stride = gridDim.x * blockDim.x;
    for (; i < n_edges; i += stride) {
        float wi = w[i];
        atomicAdd(&deg[src[i]], wi);
        atomicAdd(&deg[N_NODES + dst[i]], wi);
    }
}

__global__ void rsqrt_half_kernel(const float* __restrict__ deg,
                                  __half* __restrict__ normh, int n)
{
    int i = blockIdx.x * blockDim.x + threadIdx.x;
    if (i < n) normh[i] = __float2half(1.0f / sqrtf(deg[i]));
}

// ------- output pass: edges in registers, norm slices in LDS (f16) -------
__global__ __launch_bounds__(GBLK)
void prod_kernel(const float4* __restrict__ w4,
                 const int4* __restrict__ src4,
                 const int4* __restrict__ dst4,
                 const __half* __restrict__ srcn_h,
                 const __half* __restrict__ dstn_h,
                 float4* __restrict__ out4,
                 int n4, int n_edges, int qpb, int binsh,
                 const float* __restrict__ w,
                 const int* __restrict__ src,
                 const int* __restrict__ dst,
                 float* __restrict__ out)
{
    extern __shared__ __half lh[];
    const int q0   = blockIdx.x * qpb;
    const int qend = min(n4, q0 + qpb);
    const int t    = threadIdx.x;

    float4 pr[KMAX];
    int4   sv[KMAX], dv[KMAX];
    bool   val[KMAX];

#pragma unroll
    for (int k = 0; k < KMAX; ++k) {
        const int q = q0 + k * GBLK + t;
        val[k] = q < qend;
        if (val[k]) {
            pr[k] = w4[q];        // product accumulator starts at w
            sv[k] = src4[q];
            dv[k] = dst4[q];
        }
    }

    for (int phase = 0; phase < 2; ++phase) {
        const __half* tab = phase ? dstn_h : srcn_h;
        for (int lo = 0; lo < N_NODES; lo += binsh) {
            const int len = min(binsh, N_NODES - lo);
            const int len8 = len >> 3;
            const uint4* tsrc = (const uint4*)(tab + lo);
            uint4* ldst = (uint4*)lh;
            for (int k2 = t; k2 < len8; k2 += GBLK) ldst[k2] = tsrc[k2];
            for (int k2 = (len8 << 3) + t; k2 < len; k2 += GBLK) lh[k2] = tab[lo + k2];
            __syncthreads();

#pragma unroll
            for (int k = 0; k < KMAX; ++k) {
                if (!val[k]) continue;
                const int4 iv = phase ? dv[k] : sv[k];
                unsigned a;
                a = (unsigned)(iv.x - lo); if (a < (unsigned)len) pr[k].x *= __half2float(lh[a]);
                a = (unsigned)(iv.y - lo); if (a < (unsigned)len) pr[k].y *= __half2float(lh[a]);
                a = (unsigned)(iv.z - lo); if (a < (unsigned)len) pr[k].z *= __half2float(lh[a]);
                a = (unsigned)(iv.w - lo); if (a < (unsigned)len) pr[k].w *= __half2float(lh[a]);
            }
            __syncthreads();   // before next slice overwrites LDS
        }
    }

#pragma unroll
    for (int k = 0; k < KMAX; ++k) {
        const int q = q0 + k * GBLK + t;
        if (val[k]) out4[q] = pr[k];
    }

    if (blockIdx.x == 0 && t == 0) {   // tail edges (none for E=6.4M)
        for (int e = n4 * 4; e < n_edges; ++e)
            out[e] = __half2float(srcn_h[src[e]]) * __half2float(dstn_h[dst[e]]) * w[e];
    }
}

extern "C" void kernel_launch(void* const* d_in, const int* in_sizes, int n_in,
                              void* d_out, int out_size, void* d_ws, size_t ws_size,
                              hipStream_t stream)
{
    const float* w   = (const float*)d_in[0];
    const int*   src = (const int*)d_in[1];
    const int*   dst = (const int*)d_in[2];
    const int E  = in_sizes[0];
    const int n4 = E >> 2;
    float* out = (float*)d_out;

    // ws layout: [0, 400KB) f16 norm tables (srcn | dstn); [1MB, ...) scratch
    __half* normh = (__half*)d_ws;
    char* scratch = (char*)d_ws + (1 << 20);
    unsigned* parts = (unsigned*)scratch;
    float* degf = (float*)scratch;               // fallback f32 degrees
    size_t avail_u = (ws_size > (1u << 20)) ? (ws_size - (1 << 20)) / 4 : 0;

    // Biggest dynamic-LDS grant per kernel: 160KB -> 128 -> 80 -> 64KB.
    const int cands[3] = {163840, 131072, 81920};
    int lds_hist = 65536;
    for (int tC = 0; tC < 3; ++tC)
        if (hipFuncSetAttribute((const void*)hist_kernel,
                                hipFuncAttributeMaxDynamicSharedMemorySize,
                                cands[tC]) == hipSuccess) { lds_hist = cands[tC]; break; }
    int lds_prod = 65536;
    for (int tC = 0; tC < 3; ++tC)
        if (hipFuncSetAttribute((const void*)prod_kernel,
                                hipFuncAttributeMaxDynamicSharedMemorySize,
                                cands[tC]) == hipSuccess) { lds_prod = cands[tC]; break; }

    const int bins = lds_hist / 4;               // u32 packed degree counters
    const int P = (N_NODES + bins - 1) / bins;

    const int blk_per_cu = 163840 / lds_hist;
    int C = (256 * blk_per_cu) / P;              // 85 at P=3
    const size_t per_chunk_u = (size_t)P * (size_t)bins;
    if (avail_u < per_chunk_u) C = 0;
    else {
        int cmax = (int)(avail_u / per_chunk_u);
        if (C > cmax) C = cmax;
    }

    // XCD co-scheduling swizzle needs C % 8 == 0 (C=80 at 160KB LDS).
    int swz = 0;
    if (C >= 8) { C &= ~7; swz = 1; }

    if (C >= 1) {
        const int chunk4 = (n4 + C - 1) / C;
        hist_kernel<<<P * C, THREADS, (size_t)lds_hist, stream>>>(
            (const float4*)w, (const int4*)src, (const int4*)dst,
            w, src, dst, parts, n4, E, P, C, bins, chunk4, swz);
        reduce_rsqrt_kernel<<<(N_NODES + 255) / 256, 256, 0, stream>>>(
            parts, normh, P, C, bins);
    } else {
        hipMemsetAsync(degf, 0, (size_t)TWO_N * sizeof(float), stream);
        degree_atomic_kernel<<<2048, 256, 0, stream>>>(w, src, dst, degf, E);
        rsqrt_half_kernel<<<(TWO_N + 255) / 256, 256, 0, stream>>>(degf, normh, TWO_N);
    }

    {
        const int binsh = lds_prod / 2;          // f16 entries per slice
        const int maxq = KMAX * GBLK;            // 7168 quads/block capacity
        int C2 = (n4 + maxq - 1) / maxq;
        if (C2 < 256) C2 = 256;                  // fill all CUs
        const int qpb = (n4 + C2 - 1) / C2;      // <= 7168 by construction
        prod_kernel<<<C2, GBLK, (size_t)lds_prod, stream>>>(
            (const float4*)w, (const int4*)src, (const int4*)dst,
            normh, normh + N_NODES, (float4*)out,
            n4, E, qpb, binsh, w, src, dst, out);
    }
}